// Round 1
// baseline (342.628 us; speedup 1.0000x reference)
//
#include <hip/hip_runtime.h>
#include <math.h>

// ---------------------------------------------------------------------------
// Shapes: B=64, N=133, NFEAT=75, NHID=128
//   x:      (64,133,75)      adj: (64,133,133)
//   emb_w:  (75,150)  emb_b:(150)
//   gc1_w:  (150,256) gc1_b:(256)
//   gc2_w:  (256,128) gc2_b:(128)
//   gc3_w:  (128,75)  gc3_b:(75)
//   gc4_w:  (75,1)    gc4_b:(1)
//   fc1_w:  (132,3)   fc1_b:(3)
//   fin_w:  (4,1)     fin_b:(1)
// out: (64,1,1) -> 64 floats
// ---------------------------------------------------------------------------

// Generic tiled GEMM: C = act(A @ B [+ bias]), optionally batched via blockIdx.z.
// A: M x K (lda), B: K x N (ldb), C: M x N (ldc). 64x64 tile, BK=16,
// 256 threads, 4x4 micro-tile per thread. Zero-fill for partial tiles.
template<int RELU, int BIAS>
__global__ __launch_bounds__(256)
void gemm_tiled(const float* __restrict__ A, long sA,
                const float* __restrict__ B, long sB,
                const float* __restrict__ bias,
                float* __restrict__ C, long sC,
                int M, int K, int N, int lda, int ldb, int ldc)
{
    __shared__ float As[16][68];   // [k][m], row stride 272B (16B-aligned)
    __shared__ float Bs[16][68];   // [k][n]

    const int batch = blockIdx.z;
    A += (long)batch * sA;
    B += (long)batch * sB;
    C += (long)batch * sC;

    const int bn = blockIdx.x * 64;
    const int bm = blockIdx.y * 64;
    const int tid = threadIdx.x;
    const int tx = tid & 15;       // column group (4 cols)
    const int ty = tid >> 4;       // row group (4 rows)
    const int la_k = tid & 15, la_m = tid >> 4;   // A-tile loader coords
    const int lb_n = tid & 63, lb_k = tid >> 6;   // B-tile loader coords

    float acc[4][4] = {};

    for (int k0 = 0; k0 < K; k0 += 16) {
#pragma unroll
        for (int p = 0; p < 4; ++p) {
            int m  = la_m + p * 16;
            int gm = bm + m, gk = k0 + la_k;
            As[la_k][m] = (gm < M && gk < K) ? A[(long)gm * lda + gk] : 0.0f;
        }
#pragma unroll
        for (int p = 0; p < 4; ++p) {
            int k  = lb_k + p * 4;
            int gk = k0 + k, gn = bn + lb_n;
            Bs[k][lb_n] = (gk < K && gn < N) ? B[(long)gk * ldb + gn] : 0.0f;
        }
        __syncthreads();
#pragma unroll
        for (int k = 0; k < 16; ++k) {
            float4 av = *reinterpret_cast<const float4*>(&As[k][ty * 4]);
            float4 bv = *reinterpret_cast<const float4*>(&Bs[k][tx * 4]);
            float a[4] = {av.x, av.y, av.z, av.w};
            float b[4] = {bv.x, bv.y, bv.z, bv.w};
#pragma unroll
            for (int i = 0; i < 4; ++i)
#pragma unroll
                for (int j = 0; j < 4; ++j)
                    acc[i][j] = fmaf(a[i], b[j], acc[i][j]);
        }
        __syncthreads();
    }

#pragma unroll
    for (int i = 0; i < 4; ++i) {
        int gm = bm + ty * 4 + i;
        if (gm >= M) continue;
#pragma unroll
        for (int j = 0; j < 4; ++j) {
            int gn = bn + tx * 4 + j;
            if (gn >= N) continue;
            float v = acc[i][j];
            if (BIAS) v += bias[gn];
            if (RELU) v = fmaxf(v, 0.0f);
            C[(long)gm * ldc + gn] = v;
        }
    }
}

// Graph max-pooling: p[b,i,f] = max over {j: adj[b,i,j] > 1e-5} of y[b,j,f],
// 0 if no neighbors. y is post-ReLU (>=0) so init 0 is exact.
__global__ __launch_bounds__(128)
void pool_kernel(const float* __restrict__ adj, const float* __restrict__ y,
                 float* __restrict__ p, int N)
{
    const int i = blockIdx.x;   // node
    const int b = blockIdx.y;   // batch
    __shared__ int nbs[133];
    __shared__ int cnt;
    const int tid = threadIdx.x;
    if (tid == 0) cnt = 0;
    __syncthreads();
    const float* ar = adj + ((long)b * 133 + i) * 133;
    for (int j = tid; j < 133; j += 128)
        if (ar[j] > 1e-5f) nbs[atomicAdd(&cnt, 1)] = j;
    __syncthreads();
    const int c = cnt;
    const float* yb = y + (long)b * 133 * N;
    float* pr = p + ((long)b * 133 + i) * N;
    for (int f = tid; f < N; f += 128) {
        float m = 0.0f;
        for (int t = 0; t < c; ++t)
            m = fmaxf(m, yb[(long)nbs[t] * N + f]);
        pr[f] = m;
    }
}

// Fused tail: t4 = p3 @ gc4_w; y4 = relu(adj @ t4 + gc4_b);
// rest = y4[1:] @ fc1_w + fc1_b; out = sigmoid([y4[0], rest] @ fin_w + fin_b)
__global__ __launch_bounds__(256)
void tail_kernel(const float* __restrict__ p3,      // 8512 x 75
                 const float* __restrict__ adj,
                 const float* __restrict__ gc4_w, const float* __restrict__ gc4_b,
                 const float* __restrict__ fc1_w, const float* __restrict__ fc1_b,
                 const float* __restrict__ fin_w, const float* __restrict__ fin_b,
                 float* __restrict__ out)
{
    const int b = blockIdx.x;
    const int tid = threadIdx.x;
    __shared__ float t4[133];
    __shared__ float y4[133];
    __shared__ float r[3];

    if (tid < 133) {
        const float* row = p3 + ((long)b * 133 + tid) * 75;
        float s = 0.0f;
        for (int k = 0; k < 75; ++k) s = fmaf(row[k], gc4_w[k], s);
        t4[tid] = s;
    }
    __syncthreads();
    if (tid < 133) {
        const float* ar = adj + ((long)b * 133 + tid) * 133;
        float s = gc4_b[0];
        for (int j = 0; j < 133; ++j) s = fmaf(ar[j], t4[j], s);
        y4[tid] = fmaxf(s, 0.0f);
    }
    __syncthreads();
    if (tid < 3) {
        float s = fc1_b[tid];
        for (int j = 0; j < 132; ++j) s = fmaf(y4[1 + j], fc1_w[j * 3 + tid], s);
        r[tid] = s;
    }
    __syncthreads();
    if (tid == 0) {
        float z = fin_b[0] + y4[0] * fin_w[0] + r[0] * fin_w[1]
                + r[1] * fin_w[2] + r[2] * fin_w[3];
        out[b] = 1.0f / (1.0f + expf(-z));
    }
}

extern "C" void kernel_launch(void* const* d_in, const int* in_sizes, int n_in,
                              void* d_out, int out_size, void* d_ws, size_t ws_size,
                              hipStream_t stream)
{
    const float* x     = (const float*)d_in[0];
    const float* adj   = (const float*)d_in[1];
    const float* emb_w = (const float*)d_in[2];
    const float* emb_b = (const float*)d_in[3];
    const float* gc1_w = (const float*)d_in[4];
    const float* gc1_b = (const float*)d_in[5];
    const float* gc2_w = (const float*)d_in[6];
    const float* gc2_b = (const float*)d_in[7];
    const float* gc3_w = (const float*)d_in[8];
    const float* gc3_b = (const float*)d_in[9];
    const float* gc4_w = (const float*)d_in[10];
    const float* gc4_b = (const float*)d_in[11];
    const float* fc1_w = (const float*)d_in[12];
    const float* fc1_b = (const float*)d_in[13];
    const float* fin_w = (const float*)d_in[14];
    const float* fin_b = (const float*)d_in[15];
    float* out = (float*)d_out;

    const long MR = 8512;                    // 64*133 rows
    float* buf0 = (float*)d_ws;              // 8512*256 floats each
    float* buf1 = buf0 + MR * 256;
    float* buf2 = buf1 + MR * 256;

    dim3 blk(256);
    const long sAdj = 133L * 133;

    // 1) h0 = relu(x @ emb_w + emb_b)        buf0: 8512 x 150
    gemm_tiled<1, 1><<<dim3(3, 133, 1), blk, 0, stream>>>(
        x, 0, emb_w, 0, emb_b, buf0, 0, 8512, 75, 150, 75, 150, 150);
    // 2) t1 = h0 @ gc1_w                     buf1: 8512 x 256
    gemm_tiled<0, 0><<<dim3(4, 133, 1), blk, 0, stream>>>(
        buf0, 0, gc1_w, 0, nullptr, buf1, 0, 8512, 150, 256, 150, 256, 256);
    // 3) y1 = relu(adj @ t1 + gc1_b)         buf2: 8512 x 256 (batched)
    gemm_tiled<1, 1><<<dim3(4, 3, 64), blk, 0, stream>>>(
        adj, sAdj, buf1, 133L * 256, gc1_b, buf2, 133L * 256,
        133, 133, 256, 133, 256, 256);
    // 4) p1 = pool(y1)                       buf0: 8512 x 256
    pool_kernel<<<dim3(133, 64), 128, 0, stream>>>(adj, buf2, buf0, 256);
    // 5) t2 = p1 @ gc2_w                     buf1: 8512 x 128
    gemm_tiled<0, 0><<<dim3(2, 133, 1), blk, 0, stream>>>(
        buf0, 0, gc2_w, 0, nullptr, buf1, 0, 8512, 256, 128, 256, 128, 128);
    // 6) y2 = relu(adj @ t2 + gc2_b)         buf2: 8512 x 128
    gemm_tiled<1, 1><<<dim3(2, 3, 64), blk, 0, stream>>>(
        adj, sAdj, buf1, 133L * 128, gc2_b, buf2, 133L * 128,
        133, 133, 128, 133, 128, 128);
    // 7) p2 = pool(y2)                       buf0: 8512 x 128
    pool_kernel<<<dim3(133, 64), 128, 0, stream>>>(adj, buf2, buf0, 128);
    // 8) t3 = p2 @ gc3_w                     buf1: 8512 x 75
    gemm_tiled<0, 0><<<dim3(2, 133, 1), blk, 0, stream>>>(
        buf0, 0, gc3_w, 0, nullptr, buf1, 0, 8512, 128, 75, 128, 75, 75);
    // 9) y3 = relu(adj @ t3 + gc3_b)         buf2: 8512 x 75
    gemm_tiled<1, 1><<<dim3(2, 3, 64), blk, 0, stream>>>(
        adj, sAdj, buf1, 133L * 75, gc3_b, buf2, 133L * 75,
        133, 133, 75, 133, 75, 75);
    // 10) p3 = pool(y3)                      buf0: 8512 x 75
    pool_kernel<<<dim3(133, 64), 128, 0, stream>>>(adj, buf2, buf0, 75);
    // 11) tail -> out (64)
    tail_kernel<<<dim3(64), blk, 0, stream>>>(
        buf0, adj, gc4_w, gc4_b, fc1_w, fc1_b, fin_w, fin_b, out);
}